// Round 10
// baseline (99.365 us; speedup 1.0000x reference)
//
#include <hip/hip_runtime.h>

#define NN 16384      // nodes
#define NE 65536      // edges
#define H  32
#define BB 32
#define NPERB 512

// ---- prep1: embed (f4) + type-matrices + deg hist + type hist + zero buf1 ----
__global__ __launch_bounds__(256) void k_prep1(
    const int* __restrict__ x_nodes, const int* __restrict__ edge_index,
    const int* __restrict__ edge_attr, const float* __restrict__ node_emb,
    const float* __restrict__ edge_emb, const float* __restrict__ lin_w,
    const float* __restrict__ lin_b, float* __restrict__ x0, float* __restrict__ Wt,
    float* __restrict__ degf, int* __restrict__ tcount, float* __restrict__ zb1) {
    __shared__ int lh[16];
    int b = blockIdx.x, thr = threadIdx.x;
    if (b < 512) {                          // embed: 131072 float4 tasks
        int t = b * 256 + thr;
        int n = t >> 3, r = t & 7;
        ((float4*)x0)[t] = ((const float4*)node_emb)[x_nodes[n] * 8 + r];
    } else if (b < 768) {                   // Wt: 65536 tasks (4 layers x 16 ty)
        int w = (b - 512) * 256 + thr;      // l*16384 + ty*1024 + io
        int l = w >> 14, rest = w & 16383;
        int ty = rest >> 10, io = rest & 1023;
        float acc = lin_b[l * 1024 + io];
#pragma unroll
        for (int jj = 0; jj < 8; ++jj) {
            float e2 = fmaxf(edge_emb[(l * 16 + ty) * 8 + jj], 0.f);
            acc = fmaf(e2, lin_w[(l * 8 + jj) * 1024 + io], acc);
        }
        Wt[w] = acc;
    } else if (b < 1024) {                  // edges: deg + type hist
        if (thr < 16) lh[thr] = 0;
        __syncthreads();
        int e = (b - 768) * 256 + thr;
        int d = edge_index[NE + e];
        int ty = edge_attr[e];
        atomicAdd(&degf[d], 1.0f);
        atomicAdd(&lh[ty], 1);
        __syncthreads();
        if (thr < 16) atomicAdd(&tcount[thr], lh[thr]);
    } else {                                // zero buf1: 131072 float4 tasks
        int z = (b - 1024) * 256 + thr;
        ((float4*)zb1)[z] = make_float4(0.f, 0.f, 0.f, 0.f);
    }
}

// ---- prep2: exclusive scan of 16 type counts -> bucket cursors ----
__global__ void k_prep2(const int* __restrict__ tcount, int* __restrict__ gcursor) {
    int t = threadIdx.x;
    int c = (t < 16) ? tcount[t] : 0;
    int base = 0;
    for (int u = 0; u < 15; ++u) {
        int cu = __shfl(c, u);
        if (u < t) base += cu;
    }
    if (t < 16) gcursor[t] = base;
}

// ---- prep3: counting-sort scatter into type buckets: blist[slot]=src|dst<<14|ty<<28 ----
__global__ __launch_bounds__(256) void k_prep3(
    const int* __restrict__ edge_index, const int* __restrict__ edge_attr,
    int* __restrict__ gcursor, unsigned int* __restrict__ blist) {
    __shared__ int lh[16], lb[16];
    int thr = threadIdx.x;
    if (thr < 16) lh[thr] = 0;
    __syncthreads();
    int e = blockIdx.x * 256 + thr;
    unsigned int s = (unsigned int)edge_index[e];
    unsigned int d = (unsigned int)edge_index[NE + e];
    int ty = edge_attr[e];
    int rank = atomicAdd(&lh[ty], 1);
    __syncthreads();
    if (thr < 16) lb[thr] = atomicAdd(&gcursor[thr], lh[thr]);
    __syncthreads();
    blist[lb[ty] + rank] = s | (d << 14) | ((unsigned int)ty << 28);
}

// ---- one layer: matvec8 edges (8 lanes/edge, no shfl) + LDS in-wave transpose
//      -> wave-contiguous row atomics. Self tasks via same path. ----
// blocks [0,2048)    : edges, 32 edges/block (8 lanes each)
// blocks [2048,2560) : self,  32 nodes/block
// blocks [2560,2816) : zero next buffer (2 float4/thread), skipped when zb==0
__global__ __launch_bounds__(256, 6) void k_phase(
    const float* __restrict__ xin, float* __restrict__ xout, float* __restrict__ zb,
    const unsigned int* __restrict__ blist, const float* __restrict__ degf,
    const float* __restrict__ Wl, const float* __restrict__ Rl,
    const float* __restrict__ Bl, int relu_in) {
    int b = blockIdx.x;
    int thr = threadIdx.x;
    if (b < 2560) {
        __shared__ __align__(16) float Ms[4][8][36];
        int wv = thr >> 6;                  // wave 0..3
        int lane = thr & 63;
        int j = thr & 7;                    // lane within 8-lane group
        int gl = (thr >> 3) & 7;            // group within wave
        int is_edge = (b < 2048);
        int g = is_edge ? (b * 32 + (thr >> 3))              // edge id
                        : ((b - 2048) * 32 + (thr >> 3));    // node id
        unsigned int p = is_edge ? blist[g] : 0u;
        int s = is_edge ? (int)(p & 16383) : g;
        // full x row per lane (group-uniform addresses -> L1 broadcast)
        const float4* __restrict__ xr4 = (const float4*)(xin + s * H);
        float4 a0 = xr4[0], a1 = xr4[1], a2 = xr4[2], a3 = xr4[3],
               a4 = xr4[4], a5 = xr4[5], a6 = xr4[6], a7 = xr4[7];
        float xr[32];
#define XC(k, v) xr[4*k+0]=v.x; xr[4*k+1]=v.y; xr[4*k+2]=v.z; xr[4*k+3]=v.w;
        XC(0,a0) XC(1,a1) XC(2,a2) XC(3,a3) XC(4,a4) XC(5,a5) XC(6,a6) XC(7,a7)
#undef XC
        if (relu_in) {
#pragma unroll
            for (int k = 0; k < 32; ++k) xr[k] = fmaxf(xr[k], 0.f);
        }
        const float4* __restrict__ W4 = is_edge
            ? (const float4*)(Wl + (p >> 28) * 1024)   // type matrix (sorted: wave-hot)
            : (const float4*)Rl;                       // root matrix
        float4 acc = is_edge ? make_float4(0.f, 0.f, 0.f, 0.f)
                             : ((const float4*)Bl)[j];
#pragma unroll
        for (int i = 0; i < 32; ++i) {
            float4 w = W4[i * 8 + j];
            acc.x = fmaf(xr[i], w.x, acc.x);
            acc.y = fmaf(xr[i], w.y, acc.y);
            acc.z = fmaf(xr[i], w.z, acc.z);
            acc.w = fmaf(xr[i], w.w, acc.w);
        }
        if (is_edge) {                      // fold 1/deg before transpose
            float invd = __builtin_amdgcn_rcpf(fmaxf(degf[(p >> 14) & 16383], 1.0f));
            acc.x *= invd; acc.y *= invd; acc.z *= invd; acc.w *= invd;
        }
        // in-wave transpose through LDS (no barrier needed: same-wave DS ordering)
        *(float4*)&Ms[wv][gl][j * 4] = acc;
        // emit 8 rows as wave-contiguous atomics (2 rows per instr)
#pragma unroll
        for (int k = 0; k < 4; ++k) {
            int rloc = k * 2 + (lane >> 5);                  // row 0..7 in this wave
            int er = (b & 2047) * 32 + wv * 8 + rloc;        // edge/node id of that row
            int d;
            if (is_edge) {
                unsigned int pk = blist[er];                 // 2 addrs/wave: broadcast
                d = (int)((pk >> 14) & 16383);
            } else {
                d = er;
            }
            float v = Ms[wv][rloc][lane & 31];
            atomicAdd(&xout[d * H + (lane & 31)], v);
        }
    } else if (zb) {                        // zero next accumulator
        int t = (b - 2560) * 256 + thr;
        ((float4*)zb)[t] = make_float4(0.f, 0.f, 0.f, 0.f);
        ((float4*)zb)[t + 65536] = make_float4(0.f, 0.f, 0.f, 0.f);
    }
}

// ---- readout: one thread per output element (B x 128) ----
__global__ void k_final(const float* __restrict__ x, const int* __restrict__ metal_idx,
                        const int* __restrict__ loop_edge, const int* __restrict__ loop_pair,
                        const float* __restrict__ f_w, const float* __restrict__ f_b,
                        float* __restrict__ out) {
    int tid = blockIdx.x * blockDim.x + threadIdx.x;
    if (tid >= BB * 128) return;
    int b = tid >> 7, j = tid & 127;
    int mg = metal_idx[b] + b * NPERB;
    const float* __restrict__ xm = x + mg * H;
    int p0, p1;
    if (j < 64) {
        p0 = loop_edge[(b * 64 + j) * 2];
        p1 = loop_edge[(b * 64 + j) * 2 + 1];
    } else {
        int j2 = j - 64;
        p0 = loop_pair[(b * 64 + j2) * 2];
        p1 = loop_pair[(b * 64 + j2) * 2 + 1];
    }
    const float* __restrict__ xs = x + (b * NPERB + p0) * H;
    const float* __restrict__ xt = x + (b * NPERB + p1) * H;
    float fh = f_b[0];
    float pp = 0.f;
#pragma unroll
    for (int h = 0; h < H; ++h) {
        float m = xm[h];
        fh = fmaf(m, f_w[h], fh);
        pp += m * (xs[h] + xt[h]) - xs[h] * xt[h];
    }
    out[tid] = (j < 64) ? (pp - fh) : (-pp);
}

extern "C" void kernel_launch(void* const* d_in, const int* in_sizes, int n_in,
                              void* d_out, int out_size, void* d_ws, size_t ws_size,
                              hipStream_t stream) {
    const int*   x_nodes    = (const int*)d_in[0];
    const int*   edge_index = (const int*)d_in[1];
    const int*   edge_attr  = (const int*)d_in[2];
    const int*   metal_idx  = (const int*)d_in[3];
    const int*   loop_edge  = (const int*)d_in[4];
    const int*   loop_pair  = (const int*)d_in[5];
    const float* node_emb   = (const float*)d_in[6];
    const float* edge_emb   = (const float*)d_in[7];
    const float* lin_w      = (const float*)d_in[8];
    const float* lin_b      = (const float*)d_in[9];
    const float* root_w     = (const float*)d_in[10];
    const float* conv_b     = (const float*)d_in[11];
    const float* f_w        = (const float*)d_in[12];
    const float* f_b        = (const float*)d_in[13];
    float* out = (float*)d_out;

    float* ws   = (float*)d_ws;
    float* buf0 = ws;                          // 512K floats
    float* buf1 = buf0 + NN * H;               // 512K
    float* buf2 = buf1 + NN * H;               // 512K
    float* degf = buf2 + NN * H;               // NN       (zeroed)
    int*   tcount  = (int*)(degf + NN);        // 16       (zeroed)
    int*   gcursor = tcount + 16;              // 16       (zeroed)
    unsigned int* blist = (unsigned int*)(gcursor + 16);   // NE
    float* Wt   = (float*)(blist + NE);        // 4*16*1024

    hipMemsetAsync(degf, 0, (NN + 32) * sizeof(float), stream);

    k_prep1<<<1536, 256, 0, stream>>>(x_nodes, edge_index, edge_attr, node_emb,
                                      edge_emb, lin_w, lin_b, buf0, Wt, degf, tcount, buf1);
    k_prep2<<<1, 64, 0, stream>>>(tcount, gcursor);
    k_prep3<<<256, 256, 0, stream>>>(edge_index, edge_attr, gcursor, blist);

    // rotation: buf0->buf1 (zero buf2), buf1->buf2 (zero buf0),
    //           buf2->buf0 (zero buf1), buf0->buf1 (no zero). final reads buf1.
    k_phase<<<2816, 256, 0, stream>>>(buf0, buf1, buf2, blist, degf,
                                      Wt + 0 * 16384, root_w + 0 * 1024, conv_b + 0 * H, 0);
    k_phase<<<2816, 256, 0, stream>>>(buf1, buf2, buf0, blist, degf,
                                      Wt + 1 * 16384, root_w + 1 * 1024, conv_b + 1 * H, 1);
    k_phase<<<2816, 256, 0, stream>>>(buf2, buf0, buf1, blist, degf,
                                      Wt + 2 * 16384, root_w + 2 * 1024, conv_b + 2 * H, 1);
    k_phase<<<2560, 256, 0, stream>>>(buf0, buf1, (float*)0, blist, degf,
                                      Wt + 3 * 16384, root_w + 3 * 1024, conv_b + 3 * H, 1);

    k_final<<<16, 256, 0, stream>>>(buf1, metal_idx, loop_edge, loop_pair, f_w, f_b, out);
}

// Round 11
// 90.701 us; speedup vs baseline: 1.0955x; 1.0955x over previous
//
#include <hip/hip_runtime.h>

#define NN 16384      // nodes
#define NE 65536      // edges
#define H  32
#define BB 32
#define NPERB 512

// ---- zero degf (replaces hipMemsetAsync's ~40us fillBufferAligned) ----
__global__ __launch_bounds__(256) void k_zero(float* __restrict__ degf) {
    int t = blockIdx.x * 256 + threadIdx.x;   // 16 blocks x 256 = 4096 float4 = 64KB
    ((float4*)degf)[t] = make_float4(0.f, 0.f, 0.f, 0.f);
}

// ---- fused prep:
//  tasks [0, 512K)        : x0 = node_emb[x_nodes]            (n*32+h)
//  tasks [512K, 576K)     : Wt[l][t][i][o] per-type matrices  (all 4 layers)
//  tasks [576K, 640K)     : packed edge = src|dst<<14|ty<<28  + deg histogram
//  tasks [640K, 1152K)    : zero buf1 (first layer's accumulator)
__global__ __launch_bounds__(256) void k_prep(
    const int* __restrict__ x_nodes, const int* __restrict__ edge_index,
    const int* __restrict__ edge_attr,
    const float* __restrict__ node_emb, const float* __restrict__ edge_emb,
    const float* __restrict__ lin_w, const float* __restrict__ lin_b,
    float* __restrict__ x0, float* __restrict__ Wt,
    unsigned int* __restrict__ packed, float* __restrict__ degf,
    float* __restrict__ zbuf) {
    int t = blockIdx.x * 256 + threadIdx.x;
    if (t < 524288) {
        int n = t >> 5, h = t & 31;
        x0[t] = node_emb[x_nodes[n] * H + h];
    } else if (t < 589824) {
        int w = t - 524288;               // l*16384 + ty*1024 + io
        int l = w >> 14, rest = w & 16383;
        int ty = rest >> 10, io = rest & 1023;
        float acc = lin_b[l * 1024 + io];
#pragma unroll
        for (int j = 0; j < 8; ++j) {
            float e = fmaxf(edge_emb[(l * 16 + ty) * 8 + j], 0.f);
            acc = fmaf(e, lin_w[(l * 8 + j) * 1024 + io], acc);
        }
        Wt[w] = acc;
    } else if (t < 655360) {
        int e = t - 589824;
        unsigned int s  = (unsigned int)edge_index[e];
        unsigned int d  = (unsigned int)edge_index[NE + e];
        unsigned int ty = (unsigned int)edge_attr[e];
        packed[e] = s | (d << 14) | (ty << 28);
        atomicAdd(&degf[d], 1.0f);        // degf zeroed by k_zero
    } else {
        zbuf[t - 655360] = 0.f;           // 512K zero tasks (buf1)
    }
}

// ---- one fused layer: edge scatter (pre-scaled by 1/deg) + self root-term + zero next.
//  tasks [0, 2M)        : edge task, 32 lanes/edge, lane o owns output elem o
//  tasks [2M, 2.5M)     : self task: out[n] += x[n]@root + b
//  tasks [2.5M, 3M)     : zero the third buffer for layer l+1
__global__ __launch_bounds__(256) void k_phase(
    const float* __restrict__ xin, float* __restrict__ xout,
    float* __restrict__ zbuf,
    const unsigned int* __restrict__ packed, const float* __restrict__ degf,
    const float* __restrict__ Wt_l, const float* __restrict__ root_l,
    const float* __restrict__ b_l, int relu_in) {
    int t = blockIdx.x * 256 + threadIdx.x;
    int base = threadIdx.x & 32;          // half-wave base for shfl broadcast
    if (t < 2097152) {
        int e = t >> 5, o = t & 31;
        unsigned int p = packed[e];       // broadcast across the 32-lane group
        int s  = p & 16383;
        int d  = (p >> 14) & 16383;
        int ty = p >> 28;
        float xv = xin[s * H + o];        // coalesced 128B per half-wave
        if (relu_in) xv = fmaxf(xv, 0.f);
        float invd = __builtin_amdgcn_rcpf(fmaxf(degf[d], 1.0f));
        const float* __restrict__ W = Wt_l + ty * 1024 + o;
        float acc = 0.f;
#pragma unroll
        for (int i = 0; i < 32; ++i)
            acc = fmaf(__shfl(xv, base + i), W[i * 32], acc);
        atomicAdd(&xout[d * H + o], acc * invd);
    } else if (t < 2621440) {
        int t2 = t - 2097152;
        int o = t2 & 31;
        float xv = xin[t2];
        if (relu_in) xv = fmaxf(xv, 0.f);
        float acc = b_l[o];
#pragma unroll
        for (int i = 0; i < 32; ++i)
            acc = fmaf(__shfl(xv, base + i), root_l[i * 32 + o], acc);
        atomicAdd(&xout[t2], acc);
    } else if (zbuf) {
        zbuf[t - 2621440] = 0.f;
    }
}

// ---- readout: one thread per output element (B x 128) ----
__global__ void k_final(const float* __restrict__ x, const int* __restrict__ metal_idx,
                        const int* __restrict__ loop_edge, const int* __restrict__ loop_pair,
                        const float* __restrict__ f_w, const float* __restrict__ f_b,
                        float* __restrict__ out) {
    int tid = blockIdx.x * blockDim.x + threadIdx.x;
    if (tid >= BB * 128) return;
    int b = tid >> 7, j = tid & 127;
    int mg = metal_idx[b] + b * NPERB;
    const float* __restrict__ xm = x + mg * H;
    int p0, p1;
    if (j < 64) {
        p0 = loop_edge[(b * 64 + j) * 2];
        p1 = loop_edge[(b * 64 + j) * 2 + 1];
    } else {
        int j2 = j - 64;
        p0 = loop_pair[(b * 64 + j2) * 2];
        p1 = loop_pair[(b * 64 + j2) * 2 + 1];
    }
    const float* __restrict__ xs = x + (b * NPERB + p0) * H;
    const float* __restrict__ xt = x + (b * NPERB + p1) * H;
    float fh = f_b[0];
    float pp = 0.f;
#pragma unroll
    for (int h = 0; h < H; ++h) {
        float m = xm[h];
        fh = fmaf(m, f_w[h], fh);
        pp += m * (xs[h] + xt[h]) - xs[h] * xt[h];
    }
    out[tid] = (j < 64) ? (pp - fh) : (-pp);
}

extern "C" void kernel_launch(void* const* d_in, const int* in_sizes, int n_in,
                              void* d_out, int out_size, void* d_ws, size_t ws_size,
                              hipStream_t stream) {
    const int*   x_nodes    = (const int*)d_in[0];
    const int*   edge_index = (const int*)d_in[1];
    const int*   edge_attr  = (const int*)d_in[2];
    const int*   metal_idx  = (const int*)d_in[3];
    const int*   loop_edge  = (const int*)d_in[4];
    const int*   loop_pair  = (const int*)d_in[5];
    const float* node_emb   = (const float*)d_in[6];
    const float* edge_emb   = (const float*)d_in[7];
    const float* lin_w      = (const float*)d_in[8];
    const float* lin_b      = (const float*)d_in[9];
    const float* root_w     = (const float*)d_in[10];
    const float* conv_b     = (const float*)d_in[11];
    const float* f_w        = (const float*)d_in[12];
    const float* f_b        = (const float*)d_in[13];
    float* out = (float*)d_out;

    float* ws   = (float*)d_ws;
    float* buf0 = ws;                          // NN*H
    float* buf1 = buf0 + NN * H;               // NN*H
    float* buf2 = buf1 + NN * H;               // NN*H
    float* degf = buf2 + NN * H;               // NN (zeroed by k_zero)
    unsigned int* packed = (unsigned int*)(degf + NN);   // NE
    float* Wt   = (float*)(packed + NE);       // 4*16*1024

    k_zero<<<16, 256, 0, stream>>>(degf);

    k_prep<<<4608, 256, 0, stream>>>(x_nodes, edge_index, edge_attr, node_emb, edge_emb,
                                     lin_w, lin_b, buf0, Wt, packed, degf, buf1);

    // l=0: buf0 -> buf1, zero buf2      (relu_in = 0, x0 is raw embedding)
    // l=1: buf1 -> buf2, zero buf0      (relu_in = 1)
    // l=2: buf2 -> buf0, zero buf1
    // l=3: buf0 -> buf1, no zero
    k_phase<<<12288, 256, 0, stream>>>(buf0, buf1, buf2, packed, degf,
                                       Wt + 0 * 16384, root_w + 0 * 1024, conv_b + 0 * H, 0);
    k_phase<<<12288, 256, 0, stream>>>(buf1, buf2, buf0, packed, degf,
                                       Wt + 1 * 16384, root_w + 1 * 1024, conv_b + 1 * H, 1);
    k_phase<<<12288, 256, 0, stream>>>(buf2, buf0, buf1, packed, degf,
                                       Wt + 2 * 16384, root_w + 2 * 1024, conv_b + 2 * H, 1);
    k_phase<<<10240, 256, 0, stream>>>(buf0, buf1, (float*)0, packed, degf,
                                       Wt + 3 * 16384, root_w + 3 * 1024, conv_b + 3 * H, 1);

    k_final<<<16, 256, 0, stream>>>(buf1, metal_idx, loop_edge, loop_pair, f_w, f_b, out);
}